// Round 7
// baseline (800.445 us; speedup 1.0000x reference)
//
#include <hip/hip_runtime.h>
#include <math.h>

// Problem constants
#define TT 16384   // B*N tokens
#define HH 1024    // hidden
#define DD 2048    // expert inner dim
#define EE 8       // experts
#define MAXTILES 160  // >= EE + TT/128

typedef float f32x4 __attribute__((ext_vector_type(4)));
typedef __bf16 bf16x8 __attribute__((ext_vector_type(8)));

__device__ __forceinline__ unsigned short f2bf(float f) {
  union { float f; unsigned u; } v; v.f = f;
  unsigned r = v.u + 0x7FFFu + ((v.u >> 16) & 1u);  // RNE
  return (unsigned short)(r >> 16);
}

// async global->LDS 16B per lane; LDS dest = wave-uniform base + lane*16
__device__ __forceinline__ void gl2lds16(const unsigned short* g, unsigned short* l) {
  __builtin_amdgcn_global_load_lds(
      (const __attribute__((address_space(1))) void*)g,
      (__attribute__((address_space(3))) void*)l, 16, 0, 0);
}

// ---------------- merged transpose+convert (both weights) + accumulator init ----------------
__global__ __launch_bounds__(256) void k_transpose2(const float* __restrict__ W1s,
                                                    unsigned short* __restrict__ W1d,
                                                    const float* __restrict__ W2s,
                                                    unsigned short* __restrict__ W2d,
                                                    int* counts, float* probs_sum,
                                                    float* ent_sum, int* ticket) {
  if (blockIdx.x == 0) {
    int t0 = threadIdx.x;
    if (t0 < EE) { counts[t0] = 0; probs_sum[t0] = 0.f; }
    if (t0 == 0) { *ent_sum = 0.f; *ticket = 0; }
  }
  const int T1 = EE * (HH / 64) * (DD / 64);   // 4096 tiles for W1
  int bid = blockIdx.x;
  const float* src; unsigned short* dst; int R, C;
  if (bid < T1) { src = W1s; dst = W1d; R = HH; C = DD; }
  else          { bid -= T1; src = W2s; dst = W2d; R = DD; C = HH; }
  int tilesC = C >> 6, tilesR = R >> 6;
  int e = bid / (tilesR * tilesC);
  int rem = bid % (tilesR * tilesC);
  int tr = rem / tilesC, tc = rem % tilesC;
  const float* s = src + (size_t)e * R * C + (size_t)(tr * 64) * C + tc * 64;
  unsigned short* d = dst + (size_t)e * R * C + (size_t)(tc * 64) * R + tr * 64;

  __shared__ float t2[64][65];   // t2[c][r] = s[r][c]
  int t = threadIdx.x;
  int col = t & 63, rbase = t >> 6;
#pragma unroll
  for (int i = 0; i < 16; ++i) {
    int row = rbase + i * 4;
    t2[col][row] = s[(size_t)row * C + col];
  }
  __syncthreads();
#pragma unroll
  for (int i = 0; i < 4; ++i) {
    int p = t + i * 256;
    int rr = p >> 4, ch = (p & 15) << 2;
    ushort4 o;
    o.x = f2bf(t2[rr][ch + 0]);
    o.y = f2bf(t2[rr][ch + 1]);
    o.z = f2bf(t2[rr][ch + 2]);
    o.w = f2bf(t2[rr][ch + 3]);
    *(ushort4*)&d[(size_t)rr * R + ch] = o;
  }
}

// ---------------- router: fp64 logits+argmax, fp32 softmax/entropy, fused x->bf16,
// + inline scan in the LAST block (ticket) ----------------
__global__ __launch_bounds__(256) void k_router(const float* __restrict__ x,
                                                const float* __restrict__ Wr,
                                                const float* __restrict__ br,
                                                int* __restrict__ eidx,
                                                float* __restrict__ probs_sum,
                                                float* __restrict__ ent_sum,
                                                int* __restrict__ counts,
                                                unsigned short* __restrict__ xb,
                                                int* __restrict__ ticket,
                                                int* __restrict__ offsets,
                                                int* __restrict__ cursor,
                                                int* __restrict__ tileE,
                                                int* __restrict__ tileR0,
                                                int* __restrict__ tileEnd,
                                                int* __restrict__ nTiles,
                                                float* __restrict__ out_scalars) {
  __shared__ float s_p[EE];
  __shared__ int   s_c[EE];
  __shared__ float s_e;
  __shared__ int   s_last;
  int tid = threadIdx.x;
  if (tid < EE) { s_p[tid] = 0.f; s_c[tid] = 0; }
  if (tid == 0) s_e = 0.f;
  __syncthreads();
  int lane = tid & 63, w = tid >> 6;
  for (int tt = 0; tt < 4; ++tt) {
    int token = blockIdx.x * 16 + w * 4 + tt;
    double acc[EE];
#pragma unroll
    for (int e = 0; e < EE; ++e) acc[e] = 0.0;
    const float* xr = x + (size_t)token * HH;
    unsigned short* xo = xb + (size_t)token * HH;
#pragma unroll
    for (int i = 0; i < 4; ++i) {
      int hh = i * 256 + lane * 4;
      f32x4 xf = *(const f32x4*)&xr[hh];
      ushort4 o;
      o.x = f2bf(xf[0]); o.y = f2bf(xf[1]); o.z = f2bf(xf[2]); o.w = f2bf(xf[3]);
      *(ushort4*)&xo[hh] = o;               // fused fp32->bf16 conversion
#pragma unroll
      for (int k = 0; k < 4; ++k) {
        double xv = (double)xf[k];
        const float* wr = Wr + (size_t)(hh + k) * EE;
#pragma unroll
        for (int e = 0; e < EE; ++e) acc[e] += xv * (double)wr[e];
      }
    }
#pragma unroll
    for (int off = 32; off > 0; off >>= 1) {
#pragma unroll
      for (int e = 0; e < EE; ++e) acc[e] += __shfl_down(acc[e], off);
    }
    if (lane == 0) {
      double l[EE];
#pragma unroll
      for (int e = 0; e < EE; ++e) l[e] = acc[e] + (double)br[e];
      double m = l[0]; int am = 0;
#pragma unroll
      for (int e = 1; e < EE; ++e) { if (l[e] > m) { m = l[e]; am = e; } }  // first-max semantics
      float p[EE]; float s = 0.f;
#pragma unroll
      for (int e = 0; e < EE; ++e) { p[e] = __expf((float)(l[e] - m)); s += p[e]; }
      float inv = 1.0f / s; float ent = 0.f;
#pragma unroll
      for (int e = 0; e < EE; ++e) { p[e] *= inv; ent -= p[e] * __logf(p[e] + 1e-8f); }
      eidx[token] = am;
#pragma unroll
      for (int e = 0; e < EE; ++e) atomicAdd(&s_p[e], p[e]);
      atomicAdd(&s_e, ent);
      atomicAdd(&s_c[am], 1);
    }
  }
  __syncthreads();
  if (tid < EE) { atomicAdd(&probs_sum[tid], s_p[tid]); atomicAdd(&counts[tid], s_c[tid]); }
  if (tid == 0) atomicAdd(ent_sum, s_e);
  if (tid == 0) {
    __threadfence();
    int done = atomicAdd(ticket, 1);
    s_last = (done == (int)gridDim.x - 1) ? 1 : 0;
  }
  __syncthreads();
  if (s_last) {
    __shared__ int soff[EE + 1];
    __shared__ int tbase[EE + 1];
    __shared__ int scnt[EE];
    if (tid == 0) {
      int off = 0, tb = 0; float bal = 0.f;
      for (int e = 0; e < EE; ++e) {
        int c = atomicAdd(&counts[e], 0);          // coherent read (device-scope RMW)
        float ps = atomicAdd(&probs_sum[e], 0.f);
        scnt[e] = c; soff[e] = off; offsets[e] = off; cursor[e] = off;
        tbase[e] = tb;
        tb += (c + 127) >> 7;
        off += c;
        float pi = ps / (float)TT; bal += pi * pi;
        out_scalars[2 + e] = (float)c;             // tokens_per_expert
      }
      soff[EE] = off; offsets[EE] = off; tbase[EE] = tb;
      *nTiles = tb;
      out_scalars[0] = (float)EE * bal;                        // balance_loss
      out_scalars[1] = atomicAdd(ent_sum, 0.f) / (float)TT;    // entropy_loss
    }
    __syncthreads();
    int nt = tbase[EE];
    for (int i = tid; i < nt; i += 256) {
      int e = 0;
      while (tbase[e + 1] <= i) ++e;
      int j = i - tbase[e];
      tileE[i] = e; tileR0[i] = soff[e] + j * 128; tileEnd[i] = soff[e] + scnt[e];
    }
  }
}

// ---------------- build permutation (expert-grouped token order) ----------------
__global__ __launch_bounds__(256) void k_perm(const int* __restrict__ eidx,
                                              int* cursor, int* __restrict__ perm) {
  int t = blockIdx.x * 256 + threadIdx.x;
  int lane = threadIdx.x & 63;
  int mye = eidx[t];
  int pos = 0;
#pragma unroll
  for (int e = 0; e < EE; ++e) {
    unsigned long long mask = __ballot(mye == e);
    if (mask == 0ull) continue;
    int leader = __ffsll(mask) - 1;
    int base = 0;
    if (lane == leader) base = atomicAdd(&cursor[e], __popcll(mask));
    base = __shfl(base, leader);
    if (mye == e) pos = base + (int)__popcll(mask & ((1ull << lane) - 1ull));
  }
  perm[pos] = t;
}

// ================= 128x256-tile MFMA GEMMs (round-0 schedule, 2x MFMA per drain) =================
// Invariant found rounds 0-6: every schedule pays ~500-900cy exposed latency per
// K-step drain; MfmaUtil = MFMA-work/drain ~ 16 MFMA/wave -> 17%. This round keeps
// the fastest measured skeleton (round-0: stage -> __syncthreads drain -> ds_read +
// MFMA -> __syncthreads) and doubles MFMA per drain via BN=256: per-wave output
// 64x128 (acc[4][8], 32 MFMA/K-step). LDS 24KB single-buffered. A-panel read by
// half as many blocks; B-stage amortized over 2x rows.

// GEMM1: h = gelu(gather_perm(xb) @ Wt1[e] + b1[e]) -> bf16 hbuf (permuted rows)
__global__ __launch_bounds__(256) void k_gemm1(const unsigned short* __restrict__ xb,
                                               const unsigned short* __restrict__ Wt1,
                                               const float* __restrict__ b1,
                                               const int* __restrict__ perm,
                                               const int* __restrict__ tileE,
                                               const int* __restrict__ tileR0,
                                               const int* __restrict__ tileEnd,
                                               const int* __restrict__ nTiles,
                                               unsigned short* __restrict__ hbuf) {
  int tile = blockIdx.y;
  if (tile >= *nTiles) return;
  int e = tileE[tile], r0 = tileR0[tile], rend = tileEnd[tile];
  int c0 = blockIdx.x * 256;
  __shared__ __align__(16) unsigned short As[128 * 32];   // 8 KB
  __shared__ __align__(16) unsigned short Bs[256 * 32];   // 16 KB
  int tid = threadIdx.x, lane = tid & 63, w = tid >> 6;
  int wr = w >> 1, wc = w & 1;
  int quad = lane >> 4, l16 = lane & 15;
  // staging: wave w covers A rows [w*32,+32) (2 instr) and B rows [w*64,+64) (4 instr)
  int srow = lane >> 2, seg = lane & 3;
  int g0 = r0 + w * 32 + srow;      if (g0 >= rend) g0 = rend - 1;
  int g1 = r0 + w * 32 + 16 + srow; if (g1 >= rend) g1 = rend - 1;
  const unsigned short* aG0 = xb + (size_t)perm[g0] * HH + seg * 8;
  const unsigned short* aG1 = xb + (size_t)perm[g1] * HH + seg * 8;
  const unsigned short* bBase = Wt1 + (size_t)e * ((size_t)DD * HH);
  const unsigned short* bG[4];
  unsigned short* bL[4];
#pragma unroll
  for (int k = 0; k < 4; ++k) {
    bG[k] = bBase + (size_t)(c0 + w * 64 + k * 16 + srow) * HH + seg * 8;
    bL[k] = &Bs[(w * 64 + k * 16) * 32];
  }
  unsigned short* aL0 = &As[(w * 32 + 0) * 32];
  unsigned short* aL1 = &As[(w * 32 + 16) * 32];
  f32x4 acc[4][8] = {};
  for (int k0 = 0; k0 < HH; k0 += 32) {
    gl2lds16(aG0 + k0, aL0);
    gl2lds16(aG1 + k0, aL1);
#pragma unroll
    for (int k = 0; k < 4; ++k) gl2lds16(bG[k] + k0, bL[k]);
    __syncthreads();   // compiler drains vmcnt(0) before s_barrier
    bf16x8 a[4], b[8];
#pragma unroll
    for (int i = 0; i < 4; ++i)
      a[i] = *(const bf16x8*)&As[(wr * 64 + i * 16 + l16) * 32 + quad * 8];
#pragma unroll
    for (int j = 0; j < 8; ++j)
      b[j] = *(const bf16x8*)&Bs[(wc * 128 + j * 16 + l16) * 32 + quad * 8];
#pragma unroll
    for (int i = 0; i < 4; ++i)
#pragma unroll
      for (int j = 0; j < 8; ++j)
        acc[i][j] = __builtin_amdgcn_mfma_f32_16x16x32_bf16(a[i], b[j], acc[i][j], 0, 0, 0);
    __syncthreads();
  }
  float bias[8];
#pragma unroll
  for (int j = 0; j < 8; ++j) bias[j] = b1[e * DD + c0 + wc * 128 + j * 16 + l16];
#pragma unroll
  for (int i = 0; i < 4; ++i) {
#pragma unroll
    for (int r = 0; r < 4; ++r) {
      int gr = r0 + wr * 64 + i * 16 + quad * 4 + r;
      if (gr < rend) {
#pragma unroll
        for (int j = 0; j < 8; ++j) {
          int col = c0 + wc * 128 + j * 16 + l16;
          float v = acc[i][j][r] + bias[j];
          v = 0.5f * v * (1.0f + erff(v * 0.70710678118654752f));  // exact erf GELU
          hbuf[(size_t)gr * DD + col] = f2bf(v);
        }
      }
    }
  }
}

// GEMM2: out[perm[row]] = x + h @ Wt2[e] + b2[e]  (A rows contiguous in hbuf)
__global__ __launch_bounds__(256) void k_gemm2(const unsigned short* __restrict__ hbuf,
                                               const unsigned short* __restrict__ Wt2,
                                               const float* __restrict__ b2,
                                               const float* __restrict__ x,
                                               const int* __restrict__ perm,
                                               const int* __restrict__ tileE,
                                               const int* __restrict__ tileR0,
                                               const int* __restrict__ tileEnd,
                                               const int* __restrict__ nTiles,
                                               float* __restrict__ outp) {
  int tile = blockIdx.y;
  if (tile >= *nTiles) return;
  int e = tileE[tile], r0 = tileR0[tile], rend = tileEnd[tile];
  int c0 = blockIdx.x * 256;
  __shared__ __align__(16) unsigned short As[128 * 32];
  __shared__ __align__(16) unsigned short Bs[256 * 32];
  int tid = threadIdx.x, lane = tid & 63, w = tid >> 6;
  int wr = w >> 1, wc = w & 1;
  int quad = lane >> 4, l16 = lane & 15;
  int srow = lane >> 2, seg = lane & 3;
  int g0 = r0 + w * 32 + srow;      if (g0 >= rend) g0 = rend - 1;
  int g1 = r0 + w * 32 + 16 + srow; if (g1 >= rend) g1 = rend - 1;
  const unsigned short* aG0 = hbuf + (size_t)g0 * DD + seg * 8;
  const unsigned short* aG1 = hbuf + (size_t)g1 * DD + seg * 8;
  const unsigned short* bBase = Wt2 + (size_t)e * ((size_t)HH * DD);
  const unsigned short* bG[4];
  unsigned short* bL[4];
#pragma unroll
  for (int k = 0; k < 4; ++k) {
    bG[k] = bBase + (size_t)(c0 + w * 64 + k * 16 + srow) * DD + seg * 8;
    bL[k] = &Bs[(w * 64 + k * 16) * 32];
  }
  unsigned short* aL0 = &As[(w * 32 + 0) * 32];
  unsigned short* aL1 = &As[(w * 32 + 16) * 32];
  f32x4 acc[4][8] = {};
  for (int k0 = 0; k0 < DD; k0 += 32) {
    gl2lds16(aG0 + k0, aL0);
    gl2lds16(aG1 + k0, aL1);
#pragma unroll
    for (int k = 0; k < 4; ++k) gl2lds16(bG[k] + k0, bL[k]);
    __syncthreads();
    bf16x8 a[4], b[8];
#pragma unroll
    for (int i = 0; i < 4; ++i)
      a[i] = *(const bf16x8*)&As[(wr * 64 + i * 16 + l16) * 32 + quad * 8];
#pragma unroll
    for (int j = 0; j < 8; ++j)
      b[j] = *(const bf16x8*)&Bs[(wc * 128 + j * 16 + l16) * 32 + quad * 8];
#pragma unroll
    for (int i = 0; i < 4; ++i)
#pragma unroll
      for (int j = 0; j < 8; ++j)
        acc[i][j] = __builtin_amdgcn_mfma_f32_16x16x32_bf16(a[i], b[j], acc[i][j], 0, 0, 0);
    __syncthreads();
  }
  float bias[8];
#pragma unroll
  for (int j = 0; j < 8; ++j) bias[j] = b2[e * HH + c0 + wc * 128 + j * 16 + l16];
#pragma unroll
  for (int i = 0; i < 4; ++i) {
#pragma unroll
    for (int r = 0; r < 4; ++r) {
      int gr = r0 + wr * 64 + i * 16 + quad * 4 + r;
      if (gr < rend) {
        int tok = perm[gr];
#pragma unroll
        for (int j = 0; j < 8; ++j) {
          int col = c0 + wc * 128 + j * 16 + l16;
          size_t oi = (size_t)tok * HH + col;
          outp[oi] = x[oi] + bias[j] + acc[i][j][r];
        }
      }
    }
  }
}

extern "C" void kernel_launch(void* const* d_in, const int* in_sizes, int n_in,
                              void* d_out, int out_size, void* d_ws, size_t ws_size,
                              hipStream_t stream) {
  const float* x  = (const float*)d_in[0];
  const float* Wr = (const float*)d_in[1];
  const float* br = (const float*)d_in[2];
  const float* W1 = (const float*)d_in[3];
  const float* b1 = (const float*)d_in[4];
  const float* W2 = (const float*)d_in[5];
  const float* b2 = (const float*)d_in[6];
  float* outp = (float*)d_out;

  char* ws = (char*)d_ws;
  int*   counts    = (int*)(ws + 0);
  int*   cursor    = (int*)(ws + 64);
  int*   nTiles    = (int*)(ws + 128);
  float* probs_sum = (float*)(ws + 192);
  float* ent_sum   = (float*)(ws + 256);
  int*   offsets   = (int*)(ws + 320);
  int*   ticket    = (int*)(ws + 448);
  int*   tileE     = (int*)(ws + 512);
  int*   tileR0    = (int*)(ws + 2048);
  int*   tileEnd   = (int*)(ws + 3584);
  int*   eidx      = (int*)(ws + 8192);
  int*   perm      = (int*)(ws + 8192 + 4 * (size_t)TT);
  size_t off = 8192 + 8 * (size_t)TT;
  unsigned short* xb   = (unsigned short*)(ws + off); off += (size_t)TT * HH * 2;        // 32 MB
  unsigned short* Wt1  = (unsigned short*)(ws + off); off += (size_t)EE * DD * HH * 2;   // 32 MB
  unsigned short* Wt2  = (unsigned short*)(ws + off); off += (size_t)EE * HH * DD * 2;   // 32 MB
  unsigned short* hbuf = (unsigned short*)(ws + off); off += (size_t)TT * DD * 2;        // 64 MB

  float* out_scalars = outp + (size_t)TT * HH;

  k_transpose2<<<2 * EE * (HH / 64) * (DD / 64), 256, 0, stream>>>(
      W1, Wt1, W2, Wt2, counts, probs_sum, ent_sum, ticket);
  k_router<<<TT / 16, 256, 0, stream>>>(x, Wr, br, eidx, probs_sum, ent_sum, counts, xb,
                                        ticket, offsets, cursor, tileE, tileR0, tileEnd,
                                        nTiles, out_scalars);
  k_perm<<<TT / 256, 256, 0, stream>>>(eidx, cursor, perm);
  dim3 g1(DD / 256, MAXTILES);
  k_gemm1<<<g1, 256, 0, stream>>>(xb, Wt1, b1, perm, tileE, tileR0, tileEnd, nTiles, hbuf);
  dim3 g2(HH / 256, MAXTILES);
  k_gemm2<<<g2, 256, 0, stream>>>(hbuf, Wt2, b2, x, perm, tileE, tileR0, tileEnd, nTiles, outp);
}

// Round 8
// 598.060 us; speedup vs baseline: 1.3384x; 1.3384x over previous
//
#include <hip/hip_runtime.h>
#include <math.h>

// Problem constants
#define TT 16384   // B*N tokens
#define HH 1024    // hidden
#define DD 2048    // expert inner dim
#define EE 8       // experts
#define MAXTILES 160  // >= EE + TT/128
#define RBLK (TT / 16)  // 1024 router blocks in k_prep

typedef float f32x4 __attribute__((ext_vector_type(4)));
typedef __bf16 bf16x8 __attribute__((ext_vector_type(8)));

__device__ __forceinline__ unsigned short f2bf(float f) {
  union { float f; unsigned u; } v; v.f = f;
  unsigned r = v.u + 0x7FFFu + ((v.u >> 16) & 1u);  // RNE
  return (unsigned short)(r >> 16);
}

// async global->LDS 16B per lane; LDS dest = wave-uniform base + lane*16
__device__ __forceinline__ void gl2lds16(const unsigned short* g, unsigned short* l) {
  __builtin_amdgcn_global_load_lds(
      (const __attribute__((address_space(1))) void*)g,
      (__attribute__((address_space(3))) void*)l, 16, 0, 0);
}

// ---------------- init: zero accumulators (separate launch -> ordering guaranteed) ----------------
__global__ void k_init(int* counts, float* probs_sum, float* ent_sum, int* ticket) {
  int t = threadIdx.x;
  if (t < EE) { counts[t] = 0; probs_sum[t] = 0.f; }
  if (t == 0) { *ent_sum = 0.f; *ticket = 0; }
}

// ---------------- prep: router (blocks 0..RBLK-1) + weight transpose (rest), one launch ----------
// Router blocks are dispatched first so their latency-bound fp64/serial phases overlap the
// BW-bound transpose bulk. Last router block (device ticket) performs the scan (r6-verified).
// Transpose: [E][R][C] fp32 -> [E][C][R] bf16 in 64x64 tiles, coalesced f32 reads,
// ushort4 writes (128B segments). LDS overlaid between the two paths.
__global__ __launch_bounds__(256) void k_prep(const float* __restrict__ x,
                                              const float* __restrict__ Wr,
                                              const float* __restrict__ br,
                                              const float* __restrict__ W1s,
                                              unsigned short* __restrict__ W1d,
                                              const float* __restrict__ W2s,
                                              unsigned short* __restrict__ W2d,
                                              int* __restrict__ eidx,
                                              float* __restrict__ probs_sum,
                                              float* __restrict__ ent_sum,
                                              int* __restrict__ counts,
                                              unsigned short* __restrict__ xb,
                                              int* __restrict__ ticket,
                                              int* __restrict__ offsets,
                                              int* __restrict__ cursor,
                                              int* __restrict__ tileE,
                                              int* __restrict__ tileR0,
                                              int* __restrict__ tileEnd,
                                              int* __restrict__ nTiles,
                                              float* __restrict__ out_scalars) {
  __shared__ __align__(16) float t2[64][65];   // transpose tile; router carves scalars from it
  int tid = threadIdx.x;

  if (blockIdx.x < RBLK) {
    // ======================= router path =======================
    float* s_p   = (float*)&t2[0][0];          // [0,32)
    int*   s_c   = (int*)(s_p + EE);           // [32,64)
    float* s_e   = (float*)(s_c + EE);         // [64,68)
    int*   s_last= (int*)(s_e + 1);            // [68,72)
    if (tid < EE) { s_p[tid] = 0.f; s_c[tid] = 0; }
    if (tid == 0) *s_e = 0.f;
    __syncthreads();
    int lane = tid & 63, w = tid >> 6;
    for (int tt = 0; tt < 4; ++tt) {
      int token = blockIdx.x * 16 + w * 4 + tt;
      double acc[EE];
#pragma unroll
      for (int e = 0; e < EE; ++e) acc[e] = 0.0;
      const float* xr = x + (size_t)token * HH;
      unsigned short* xo = xb + (size_t)token * HH;
#pragma unroll
      for (int i = 0; i < 4; ++i) {
        int hh = i * 256 + lane * 4;
        f32x4 xf = *(const f32x4*)&xr[hh];
        ushort4 o;
        o.x = f2bf(xf[0]); o.y = f2bf(xf[1]); o.z = f2bf(xf[2]); o.w = f2bf(xf[3]);
        *(ushort4*)&xo[hh] = o;               // fused fp32->bf16 conversion
#pragma unroll
        for (int k = 0; k < 4; ++k) {
          double xv = (double)xf[k];
          const float* wr = Wr + (size_t)(hh + k) * EE;
#pragma unroll
          for (int e = 0; e < EE; ++e) acc[e] += xv * (double)wr[e];
        }
      }
#pragma unroll
      for (int off = 32; off > 0; off >>= 1) {
#pragma unroll
        for (int e = 0; e < EE; ++e) acc[e] += __shfl_down(acc[e], off);
      }
      if (lane == 0) {
        double l[EE];
#pragma unroll
        for (int e = 0; e < EE; ++e) l[e] = acc[e] + (double)br[e];
        double m = l[0]; int am = 0;
#pragma unroll
        for (int e = 1; e < EE; ++e) { if (l[e] > m) { m = l[e]; am = e; } }  // first-max
        float p[EE]; float s = 0.f;
#pragma unroll
        for (int e = 0; e < EE; ++e) { p[e] = __expf((float)(l[e] - m)); s += p[e]; }
        float inv = 1.0f / s; float ent = 0.f;
#pragma unroll
        for (int e = 0; e < EE; ++e) { p[e] *= inv; ent -= p[e] * __logf(p[e] + 1e-8f); }
        eidx[token] = am;
#pragma unroll
        for (int e = 0; e < EE; ++e) atomicAdd(&s_p[e], p[e]);
        atomicAdd(s_e, ent);
        atomicAdd(&s_c[am], 1);
      }
    }
    __syncthreads();
    if (tid < EE) { atomicAdd(&probs_sum[tid], s_p[tid]); atomicAdd(&counts[tid], s_c[tid]); }
    if (tid == 0) atomicAdd(ent_sum, *s_e);
    if (tid == 0) {
      __threadfence();
      int done = atomicAdd(ticket, 1);
      *s_last = (done == RBLK - 1) ? 1 : 0;
    }
    __syncthreads();
    if (*s_last) {
      int* soff  = (int*)&t2[2][0];            // well past the scalar carve
      int* tbase = soff + (EE + 1);
      int* scnt  = tbase + (EE + 1);
      if (tid == 0) {
        int off = 0, tb = 0; float bal = 0.f;
        for (int e = 0; e < EE; ++e) {
          int c = atomicAdd(&counts[e], 0);          // coherent read (device-scope RMW)
          float ps = atomicAdd(&probs_sum[e], 0.f);
          scnt[e] = c; soff[e] = off; offsets[e] = off; cursor[e] = off;
          tbase[e] = tb;
          tb += (c + 127) >> 7;
          off += c;
          float pi = ps / (float)TT; bal += pi * pi;
          out_scalars[2 + e] = (float)c;             // tokens_per_expert
        }
        soff[EE] = off; offsets[EE] = off; tbase[EE] = tb;
        *nTiles = tb;
        out_scalars[0] = (float)EE * bal;                        // balance_loss
        out_scalars[1] = atomicAdd(ent_sum, 0.f) / (float)TT;    // entropy_loss
      }
      __syncthreads();
      int nt = tbase[EE];
      for (int i = tid; i < nt; i += 256) {
        int e = 0;
        while (tbase[e + 1] <= i) ++e;
        int j = i - tbase[e];
        tileE[i] = e; tileR0[i] = soff[e] + j * 128; tileEnd[i] = soff[e] + scnt[e];
      }
    }
  } else {
    // ======================= transpose path =======================
    const int T1 = EE * (HH / 64) * (DD / 64);   // 4096 tiles for W1
    int bid = blockIdx.x - RBLK;
    const float* src; unsigned short* dst; int R, C;
    if (bid < T1) { src = W1s; dst = W1d; R = HH; C = DD; }
    else          { bid -= T1; src = W2s; dst = W2d; R = DD; C = HH; }
    int tilesC = C >> 6, tilesR = R >> 6;
    int e = bid / (tilesR * tilesC);
    int rem = bid % (tilesR * tilesC);
    int tr = rem / tilesC, tc = rem % tilesC;
    const float* s = src + (size_t)e * R * C + (size_t)(tr * 64) * C + tc * 64;
    unsigned short* d = dst + (size_t)e * R * C + (size_t)(tc * 64) * R + tr * 64;
    int col = tid & 63, rbase = tid >> 6;
#pragma unroll
    for (int i = 0; i < 16; ++i) {
      int row = rbase + i * 4;
      t2[col][row] = s[(size_t)row * C + col];
    }
    __syncthreads();
#pragma unroll
    for (int i = 0; i < 4; ++i) {
      int p = tid + i * 256;
      int rr = p >> 4, ch = (p & 15) << 2;
      ushort4 o;
      o.x = f2bf(t2[rr][ch + 0]);
      o.y = f2bf(t2[rr][ch + 1]);
      o.z = f2bf(t2[rr][ch + 2]);
      o.w = f2bf(t2[rr][ch + 3]);
      *(ushort4*)&d[(size_t)rr * R + ch] = o;
    }
  }
}

// ---------------- build permutation (expert-grouped token order) ----------------
__global__ __launch_bounds__(256) void k_perm(const int* __restrict__ eidx,
                                              int* cursor, int* __restrict__ perm) {
  int t = blockIdx.x * 256 + threadIdx.x;
  int lane = threadIdx.x & 63;
  int mye = eidx[t];
  int pos = 0;
#pragma unroll
  for (int e = 0; e < EE; ++e) {
    unsigned long long mask = __ballot(mye == e);
    if (mask == 0ull) continue;
    int leader = __ffsll(mask) - 1;
    int base = 0;
    if (lane == leader) base = atomicAdd(&cursor[e], __popcll(mask));
    base = __shfl(base, leader);
    if (mye == e) pos = base + (int)__popcll(mask & ((1ull << lane) - 1ull));
  }
  perm[pos] = t;
}

// ================= 128x128-tile MFMA GEMMs (round-0 skeleton — best measured, 158us) ============
// Per K-step(32): stage A(128x32)+B(128x32) via global_load_lds x4/wave,
// barrier, 8x ds_read_b128 frags, 16 MFMA 16x16x32, barrier.
// Rounds 1-7 established: counted-vmcnt rings, phase splits, BK=64, BN=256 all lose to
// this skeleton's occupancy-driven TLP (76 VGPR, 16KB LDS, ~22.7% occ). Do not touch.

// GEMM1: h = gelu(gather_perm(xb) @ Wt1[e] + b1[e]) -> bf16 hbuf (permuted rows)
__global__ __launch_bounds__(256) void k_gemm1(const unsigned short* __restrict__ xb,
                                               const unsigned short* __restrict__ Wt1,
                                               const float* __restrict__ b1,
                                               const int* __restrict__ perm,
                                               const int* __restrict__ tileE,
                                               const int* __restrict__ tileR0,
                                               const int* __restrict__ tileEnd,
                                               const int* __restrict__ nTiles,
                                               unsigned short* __restrict__ hbuf) {
  int tile = blockIdx.y;
  if (tile >= *nTiles) return;
  int e = tileE[tile], r0 = tileR0[tile], rend = tileEnd[tile];
  int c0 = blockIdx.x * 128;
  __shared__ __align__(16) unsigned short As[128 * 32];
  __shared__ __align__(16) unsigned short Bs[128 * 32];
  int tid = threadIdx.x, lane = tid & 63, w = tid >> 6;
  int wr = w >> 1, wc = w & 1;
  int quad = lane >> 4, l16 = lane & 15;
  int srow = lane >> 2, seg = lane & 3;
  int ar0 = w * 32 + srow, ar1 = ar0 + 16;
  int g0 = r0 + ar0; if (g0 >= rend) g0 = rend - 1;
  int g1 = r0 + ar1; if (g1 >= rend) g1 = rend - 1;
  const unsigned short* aG0 = xb + (size_t)perm[g0] * HH + seg * 8;
  const unsigned short* aG1 = xb + (size_t)perm[g1] * HH + seg * 8;
  const unsigned short* bBase = Wt1 + (size_t)e * ((size_t)DD * HH);
  const unsigned short* bG0 = bBase + (size_t)(c0 + ar0) * HH + seg * 8;
  const unsigned short* bG1 = bBase + (size_t)(c0 + ar1) * HH + seg * 8;
  unsigned short* aL0 = &As[(w * 32 + 0) * 32];
  unsigned short* aL1 = &As[(w * 32 + 16) * 32];
  unsigned short* bL0 = &Bs[(w * 32 + 0) * 32];
  unsigned short* bL1 = &Bs[(w * 32 + 16) * 32];
  f32x4 acc[4][4] = {};
  for (int k0 = 0; k0 < HH; k0 += 32) {
    gl2lds16(aG0 + k0, aL0);
    gl2lds16(aG1 + k0, aL1);
    gl2lds16(bG0 + k0, bL0);
    gl2lds16(bG1 + k0, bL1);
    __syncthreads();   // compiler drains vmcnt(0) before s_barrier
    bf16x8 a[4], b[4];
#pragma unroll
    for (int i = 0; i < 4; ++i)
      a[i] = *(const bf16x8*)&As[(wr * 64 + i * 16 + l16) * 32 + quad * 8];
#pragma unroll
    for (int j = 0; j < 4; ++j)
      b[j] = *(const bf16x8*)&Bs[(wc * 64 + j * 16 + l16) * 32 + quad * 8];
#pragma unroll
    for (int i = 0; i < 4; ++i)
#pragma unroll
      for (int j = 0; j < 4; ++j)
        acc[i][j] = __builtin_amdgcn_mfma_f32_16x16x32_bf16(a[i], b[j], acc[i][j], 0, 0, 0);
    __syncthreads();
  }
  float bias[4];
#pragma unroll
  for (int j = 0; j < 4; ++j) bias[j] = b1[e * DD + c0 + wc * 64 + j * 16 + l16];
#pragma unroll
  for (int i = 0; i < 4; ++i) {
#pragma unroll
    for (int r = 0; r < 4; ++r) {
      int gr = r0 + wr * 64 + i * 16 + quad * 4 + r;
      if (gr < rend) {
#pragma unroll
        for (int j = 0; j < 4; ++j) {
          int col = c0 + wc * 64 + j * 16 + l16;
          float v = acc[i][j][r] + bias[j];
          v = 0.5f * v * (1.0f + erff(v * 0.70710678118654752f));  // exact erf GELU
          hbuf[(size_t)gr * DD + col] = f2bf(v);
        }
      }
    }
  }
}

// GEMM2: out[perm[row]] = x + h @ Wt2[e] + b2[e]  (A rows contiguous in hbuf)
__global__ __launch_bounds__(256) void k_gemm2(const unsigned short* __restrict__ hbuf,
                                               const unsigned short* __restrict__ Wt2,
                                               const float* __restrict__ b2,
                                               const float* __restrict__ x,
                                               const int* __restrict__ perm,
                                               const int* __restrict__ tileE,
                                               const int* __restrict__ tileR0,
                                               const int* __restrict__ tileEnd,
                                               const int* __restrict__ nTiles,
                                               float* __restrict__ outp) {
  int tile = blockIdx.y;
  if (tile >= *nTiles) return;
  int e = tileE[tile], r0 = tileR0[tile], rend = tileEnd[tile];
  int c0 = blockIdx.x * 128;
  __shared__ __align__(16) unsigned short As[128 * 32];
  __shared__ __align__(16) unsigned short Bs[128 * 32];
  int tid = threadIdx.x, lane = tid & 63, w = tid >> 6;
  int wr = w >> 1, wc = w & 1;
  int quad = lane >> 4, l16 = lane & 15;
  int srow = lane >> 2, seg = lane & 3;
  int ar0 = w * 32 + srow, ar1 = ar0 + 16;
  int g0 = r0 + ar0; if (g0 >= rend) g0 = rend - 1;
  int g1 = r0 + ar1; if (g1 >= rend) g1 = rend - 1;
  const unsigned short* aG0 = hbuf + (size_t)g0 * DD + seg * 8;
  const unsigned short* aG1 = hbuf + (size_t)g1 * DD + seg * 8;
  const unsigned short* bBase = Wt2 + (size_t)e * ((size_t)HH * DD);
  const unsigned short* bG0 = bBase + (size_t)(c0 + ar0) * DD + seg * 8;
  const unsigned short* bG1 = bBase + (size_t)(c0 + ar1) * DD + seg * 8;
  unsigned short* aL0 = &As[(w * 32 + 0) * 32];
  unsigned short* aL1 = &As[(w * 32 + 16) * 32];
  unsigned short* bL0 = &Bs[(w * 32 + 0) * 32];
  unsigned short* bL1 = &Bs[(w * 32 + 16) * 32];
  f32x4 acc[4][4] = {};
  for (int k0 = 0; k0 < DD; k0 += 32) {
    gl2lds16(aG0 + k0, aL0);
    gl2lds16(aG1 + k0, aL1);
    gl2lds16(bG0 + k0, bL0);
    gl2lds16(bG1 + k0, bL1);
    __syncthreads();
    bf16x8 a[4], b[4];
#pragma unroll
    for (int i = 0; i < 4; ++i)
      a[i] = *(const bf16x8*)&As[(wr * 64 + i * 16 + l16) * 32 + quad * 8];
#pragma unroll
    for (int j = 0; j < 4; ++j)
      b[j] = *(const bf16x8*)&Bs[(wc * 64 + j * 16 + l16) * 32 + quad * 8];
#pragma unroll
    for (int i = 0; i < 4; ++i)
#pragma unroll
      for (int j = 0; j < 4; ++j)
        acc[i][j] = __builtin_amdgcn_mfma_f32_16x16x32_bf16(a[i], b[j], acc[i][j], 0, 0, 0);
    __syncthreads();
  }
  float bias[4];
#pragma unroll
  for (int j = 0; j < 4; ++j) bias[j] = b2[e * HH + c0 + wc * 64 + j * 16 + l16];
#pragma unroll
  for (int i = 0; i < 4; ++i) {
#pragma unroll
    for (int r = 0; r < 4; ++r) {
      int gr = r0 + wr * 64 + i * 16 + quad * 4 + r;
      if (gr < rend) {
        int tok = perm[gr];
#pragma unroll
        for (int j = 0; j < 4; ++j) {
          int col = c0 + wc * 64 + j * 16 + l16;
          size_t oi = (size_t)tok * HH + col;
          outp[oi] = x[oi] + bias[j] + acc[i][j][r];
        }
      }
    }
  }
}

extern "C" void kernel_launch(void* const* d_in, const int* in_sizes, int n_in,
                              void* d_out, int out_size, void* d_ws, size_t ws_size,
                              hipStream_t stream) {
  const float* x  = (const float*)d_in[0];
  const float* Wr = (const float*)d_in[1];
  const float* br = (const float*)d_in[2];
  const float* W1 = (const float*)d_in[3];
  const float* b1 = (const float*)d_in[4];
  const float* W2 = (const float*)d_in[5];
  const float* b2 = (const float*)d_in[6];
  float* outp = (float*)d_out;

  char* ws = (char*)d_ws;
  int*   counts    = (int*)(ws + 0);
  int*   cursor    = (int*)(ws + 64);
  int*   nTiles    = (int*)(ws + 128);
  float* probs_sum = (float*)(ws + 192);
  float* ent_sum   = (float*)(ws + 256);
  int*   offsets   = (int*)(ws + 320);
  int*   ticket    = (int*)(ws + 448);
  int*   tileE     = (int*)(ws + 512);
  int*   tileR0    = (int*)(ws + 2048);
  int*   tileEnd   = (int*)(ws + 3584);
  int*   eidx      = (int*)(ws + 8192);
  int*   perm      = (int*)(ws + 8192 + 4 * (size_t)TT);
  size_t off = 8192 + 8 * (size_t)TT;
  unsigned short* xb   = (unsigned short*)(ws + off); off += (size_t)TT * HH * 2;        // 32 MB
  unsigned short* Wt1  = (unsigned short*)(ws + off); off += (size_t)EE * DD * HH * 2;   // 32 MB
  unsigned short* Wt2  = (unsigned short*)(ws + off); off += (size_t)EE * HH * DD * 2;   // 32 MB
  unsigned short* hbuf = (unsigned short*)(ws + off); off += (size_t)TT * DD * 2;        // 64 MB

  float* out_scalars = outp + (size_t)TT * HH;

  k_init<<<1, 64, 0, stream>>>(counts, probs_sum, ent_sum, ticket);
  int prep_grid = RBLK + 2 * EE * (HH / 64) * (DD / 64);   // 1024 router + 8192 transpose
  k_prep<<<prep_grid, 256, 0, stream>>>(x, Wr, br, W1, Wt1, W2, Wt2,
                                        eidx, probs_sum, ent_sum, counts, xb,
                                        ticket, offsets, cursor,
                                        tileE, tileR0, tileEnd, nTiles, out_scalars);
  k_perm<<<TT / 256, 256, 0, stream>>>(eidx, cursor, perm);
  dim3 g1(DD / 128, MAXTILES);
  k_gemm1<<<g1, 256, 0, stream>>>(xb, Wt1, b1, perm, tileE, tileR0, tileEnd, nTiles, hbuf);
  dim3 g2(HH / 128, MAXTILES);
  k_gemm2<<<g2, 256, 0, stream>>>(hbuf, Wt2, b2, x, perm, tileE, tileR0, tileEnd, nTiles, outp);
}

// Round 9
// 585.200 us; speedup vs baseline: 1.3678x; 1.0220x over previous
//
#include <hip/hip_runtime.h>
#include <math.h>

// Problem constants
#define TT 16384   // B*N tokens
#define HH 1024    // hidden
#define DD 2048    // expert inner dim
#define EE 8       // experts
#define MAXTILES 160  // >= EE + TT/128

typedef float f32x4 __attribute__((ext_vector_type(4)));
typedef __bf16 bf16x8 __attribute__((ext_vector_type(8)));

__device__ __forceinline__ unsigned short f2bf(float f) {
  union { float f; unsigned u; } v; v.f = f;
  unsigned r = v.u + 0x7FFFu + ((v.u >> 16) & 1u);  // RNE
  return (unsigned short)(r >> 16);
}

// async global->LDS 16B per lane; LDS dest = wave-uniform base + lane*16
__device__ __forceinline__ void gl2lds16(const unsigned short* g, unsigned short* l) {
  __builtin_amdgcn_global_load_lds(
      (const __attribute__((address_space(1))) void*)g,
      (__attribute__((address_space(3))) void*)l, 16, 0, 0);
}

// ---------------- merged transpose+convert (both weights) + accumulator init ----------------
// Standalone (r5/r6-verified): low VGPR -> high occupancy -> BW-bound path runs fast.
// r8 lesson: merging this with the fp64 router (VGPR 156) starved it to 1.17 TB/s.
__global__ __launch_bounds__(256) void k_transpose2(const float* __restrict__ W1s,
                                                    unsigned short* __restrict__ W1d,
                                                    const float* __restrict__ W2s,
                                                    unsigned short* __restrict__ W2d,
                                                    int* counts, float* probs_sum,
                                                    float* ent_sum, int* ticket) {
  if (blockIdx.x == 0) {
    int t0 = threadIdx.x;
    if (t0 < EE) { counts[t0] = 0; probs_sum[t0] = 0.f; }
    if (t0 == 0) { *ent_sum = 0.f; *ticket = 0; }
  }
  const int T1 = EE * (HH / 64) * (DD / 64);   // 4096 tiles for W1
  int bid = blockIdx.x;
  const float* src; unsigned short* dst; int R, C;
  if (bid < T1) { src = W1s; dst = W1d; R = HH; C = DD; }
  else          { bid -= T1; src = W2s; dst = W2d; R = DD; C = HH; }
  int tilesC = C >> 6, tilesR = R >> 6;
  int e = bid / (tilesR * tilesC);
  int rem = bid % (tilesR * tilesC);
  int tr = rem / tilesC, tc = rem % tilesC;
  const float* s = src + (size_t)e * R * C + (size_t)(tr * 64) * C + tc * 64;
  unsigned short* d = dst + (size_t)e * R * C + (size_t)(tc * 64) * R + tr * 64;

  __shared__ float t2[64][65];   // t2[c][r] = s[r][c]
  int t = threadIdx.x;
  int col = t & 63, rbase = t >> 6;
#pragma unroll
  for (int i = 0; i < 16; ++i) {
    int row = rbase + i * 4;
    t2[col][row] = s[(size_t)row * C + col];
  }
  __syncthreads();
#pragma unroll
  for (int i = 0; i < 4; ++i) {
    int p = t + i * 256;
    int rr = p >> 4, ch = (p & 15) << 2;
    ushort4 o;
    o.x = f2bf(t2[rr][ch + 0]);
    o.y = f2bf(t2[rr][ch + 1]);
    o.z = f2bf(t2[rr][ch + 2]);
    o.w = f2bf(t2[rr][ch + 3]);
    *(ushort4*)&d[(size_t)rr * R + ch] = o;
  }
}

// ---------------- router: fp64 logits+argmax, fp32 softmax/entropy, fused x->bf16,
// + inline scan in the LAST block (device ticket; r6-verified) ----------------
__global__ __launch_bounds__(256) void k_router(const float* __restrict__ x,
                                                const float* __restrict__ Wr,
                                                const float* __restrict__ br,
                                                int* __restrict__ eidx,
                                                float* __restrict__ probs_sum,
                                                float* __restrict__ ent_sum,
                                                int* __restrict__ counts,
                                                unsigned short* __restrict__ xb,
                                                int* __restrict__ ticket,
                                                int* __restrict__ offsets,
                                                int* __restrict__ cursor,
                                                int* __restrict__ tileE,
                                                int* __restrict__ tileR0,
                                                int* __restrict__ tileEnd,
                                                int* __restrict__ nTiles,
                                                float* __restrict__ out_scalars) {
  __shared__ float s_p[EE];
  __shared__ int   s_c[EE];
  __shared__ float s_e;
  __shared__ int   s_last;
  int tid = threadIdx.x;
  if (tid < EE) { s_p[tid] = 0.f; s_c[tid] = 0; }
  if (tid == 0) s_e = 0.f;
  __syncthreads();
  int lane = tid & 63, w = tid >> 6;
  for (int tt = 0; tt < 4; ++tt) {
    int token = blockIdx.x * 16 + w * 4 + tt;
    double acc[EE];
#pragma unroll
    for (int e = 0; e < EE; ++e) acc[e] = 0.0;
    const float* xr = x + (size_t)token * HH;
    unsigned short* xo = xb + (size_t)token * HH;
#pragma unroll
    for (int i = 0; i < 4; ++i) {
      int hh = i * 256 + lane * 4;
      f32x4 xf = *(const f32x4*)&xr[hh];
      ushort4 o;
      o.x = f2bf(xf[0]); o.y = f2bf(xf[1]); o.z = f2bf(xf[2]); o.w = f2bf(xf[3]);
      *(ushort4*)&xo[hh] = o;               // fused fp32->bf16 conversion
#pragma unroll
      for (int k = 0; k < 4; ++k) {
        double xv = (double)xf[k];
        const float* wr = Wr + (size_t)(hh + k) * EE;
#pragma unroll
        for (int e = 0; e < EE; ++e) acc[e] += xv * (double)wr[e];
      }
    }
#pragma unroll
    for (int off = 32; off > 0; off >>= 1) {
#pragma unroll
      for (int e = 0; e < EE; ++e) acc[e] += __shfl_down(acc[e], off);
    }
    if (lane == 0) {
      double l[EE];
#pragma unroll
      for (int e = 0; e < EE; ++e) l[e] = acc[e] + (double)br[e];
      double m = l[0]; int am = 0;
#pragma unroll
      for (int e = 1; e < EE; ++e) { if (l[e] > m) { m = l[e]; am = e; } }  // first-max semantics
      float p[EE]; float s = 0.f;
#pragma unroll
      for (int e = 0; e < EE; ++e) { p[e] = __expf((float)(l[e] - m)); s += p[e]; }
      float inv = 1.0f / s; float ent = 0.f;
#pragma unroll
      for (int e = 0; e < EE; ++e) { p[e] *= inv; ent -= p[e] * __logf(p[e] + 1e-8f); }
      eidx[token] = am;
#pragma unroll
      for (int e = 0; e < EE; ++e) atomicAdd(&s_p[e], p[e]);
      atomicAdd(&s_e, ent);
      atomicAdd(&s_c[am], 1);
    }
  }
  __syncthreads();
  if (tid < EE) { atomicAdd(&probs_sum[tid], s_p[tid]); atomicAdd(&counts[tid], s_c[tid]); }
  if (tid == 0) atomicAdd(ent_sum, s_e);
  if (tid == 0) {
    __threadfence();
    int done = atomicAdd(ticket, 1);
    s_last = (done == (int)gridDim.x - 1) ? 1 : 0;
  }
  __syncthreads();
  if (s_last) {
    __shared__ int soff[EE + 1];
    __shared__ int tbase[EE + 1];
    __shared__ int scnt[EE];
    if (tid == 0) {
      int off = 0, tb = 0; float bal = 0.f;
      for (int e = 0; e < EE; ++e) {
        int c = atomicAdd(&counts[e], 0);          // coherent read (device-scope RMW)
        float ps = atomicAdd(&probs_sum[e], 0.f);
        scnt[e] = c; soff[e] = off; offsets[e] = off; cursor[e] = off;
        tbase[e] = tb;
        tb += (c + 127) >> 7;
        off += c;
        float pi = ps / (float)TT; bal += pi * pi;
        out_scalars[2 + e] = (float)c;             // tokens_per_expert
      }
      soff[EE] = off; offsets[EE] = off; tbase[EE] = tb;
      *nTiles = tb;
      out_scalars[0] = (float)EE * bal;                        // balance_loss
      out_scalars[1] = atomicAdd(ent_sum, 0.f) / (float)TT;    // entropy_loss
    }
    __syncthreads();
    int nt = tbase[EE];
    for (int i = tid; i < nt; i += 256) {
      int e = 0;
      while (tbase[e + 1] <= i) ++e;
      int j = i - tbase[e];
      tileE[i] = e; tileR0[i] = soff[e] + j * 128; tileEnd[i] = soff[e] + scnt[e];
    }
  }
}

// ---------------- build permutation (expert-grouped token order) ----------------
__global__ __launch_bounds__(256) void k_perm(const int* __restrict__ eidx,
                                              int* cursor, int* __restrict__ perm) {
  int t = blockIdx.x * 256 + threadIdx.x;
  int lane = threadIdx.x & 63;
  int mye = eidx[t];
  int pos = 0;
#pragma unroll
  for (int e = 0; e < EE; ++e) {
    unsigned long long mask = __ballot(mye == e);
    if (mask == 0ull) continue;
    int leader = __ffsll(mask) - 1;
    int base = 0;
    if (lane == leader) base = atomicAdd(&cursor[e], __popcll(mask));
    base = __shfl(base, leader);
    if (mye == e) pos = base + (int)__popcll(mask & ((1ull << lane) - 1ull));
  }
  perm[pos] = t;
}

// ================= 128x128-tile MFMA GEMMs: r0 geometry + ROTATED double-buffer =================
// r0 (158us): stage -> sync(drain) -> compute -> sync  => the drain waits on loads issued
// 0 cycles earlier: full HBM/L2 latency exposed every K-step.
// This round, SAME geometry (256 thr, 4 waves, acc[4][4], VGPR ~80), but rotated:
//   sync(drain aged loads) -> stage(OTHER buffer) -> compute(current buffer)
// Four DISTINCT __shared__ arrays (As0/Bs0/As1/Bs1) so alias analysis cannot insert an
// extra vmcnt wait between the stage-issue and the other buffer's ds_reads. The barrier
// drain now waits on loads aged by one full compute phase. LDS 32 KB (cap 5 blk/CU,
// above grid avg ~4) -> occupancy unchanged.

#define GEMM_COMPUTE(AS, BS)                                                   \
  {                                                                            \
    bf16x8 a[4], b[4];                                                         \
    _Pragma("unroll") for (int i = 0; i < 4; ++i)                              \
        a[i] = *(const bf16x8*)&AS[(wr * 64 + i * 16 + l16) * 32 + quad * 8];  \
    _Pragma("unroll") for (int j = 0; j < 4; ++j)                              \
        b[j] = *(const bf16x8*)&BS[(wc * 64 + j * 16 + l16) * 32 + quad * 8];  \
    _Pragma("unroll") for (int i = 0; i < 4; ++i)                              \
        _Pragma("unroll") for (int j = 0; j < 4; ++j)                          \
            acc[i][j] = __builtin_amdgcn_mfma_f32_16x16x32_bf16(               \
                a[i], b[j], acc[i][j], 0, 0, 0);                               \
  }

#define GEMM_STAGE(AS, BS, KOFF)                                               \
  {                                                                            \
    gl2lds16(aG0 + (KOFF), AS + base0);                                        \
    gl2lds16(aG1 + (KOFF), AS + base1);                                        \
    gl2lds16(bG0 + (KOFF), BS + base0);                                        \
    gl2lds16(bG1 + (KOFF), BS + base1);                                        \
  }

// GEMM1: h = gelu(gather_perm(xb) @ Wt1[e] + b1[e]) -> bf16 hbuf (permuted rows)
__global__ __launch_bounds__(256) void k_gemm1(const unsigned short* __restrict__ xb,
                                               const unsigned short* __restrict__ Wt1,
                                               const float* __restrict__ b1,
                                               const int* __restrict__ perm,
                                               const int* __restrict__ tileE,
                                               const int* __restrict__ tileR0,
                                               const int* __restrict__ tileEnd,
                                               const int* __restrict__ nTiles,
                                               unsigned short* __restrict__ hbuf) {
  int tile = blockIdx.y;
  if (tile >= *nTiles) return;
  int e = tileE[tile], r0 = tileR0[tile], rend = tileEnd[tile];
  int c0 = blockIdx.x * 128;
  __shared__ __align__(16) unsigned short As0[128 * 32];
  __shared__ __align__(16) unsigned short Bs0[128 * 32];
  __shared__ __align__(16) unsigned short As1[128 * 32];
  __shared__ __align__(16) unsigned short Bs1[128 * 32];
  int tid = threadIdx.x, lane = tid & 63, w = tid >> 6;
  int wr = w >> 1, wc = w & 1;
  int quad = lane >> 4, l16 = lane & 15;
  int srow = lane >> 2, seg = lane & 3;
  int ar0 = w * 32 + srow, ar1 = ar0 + 16;
  int g0 = r0 + ar0; if (g0 >= rend) g0 = rend - 1;
  int g1 = r0 + ar1; if (g1 >= rend) g1 = rend - 1;
  const unsigned short* aG0 = xb + (size_t)perm[g0] * HH + seg * 8;
  const unsigned short* aG1 = xb + (size_t)perm[g1] * HH + seg * 8;
  const unsigned short* bBase = Wt1 + (size_t)e * ((size_t)DD * HH);
  const unsigned short* bG0 = bBase + (size_t)(c0 + ar0) * HH + seg * 8;
  const unsigned short* bG1 = bBase + (size_t)(c0 + ar1) * HH + seg * 8;
  const int base0 = (w * 32 + 0) * 32, base1 = (w * 32 + 16) * 32;
  f32x4 acc[4][4] = {};
  GEMM_STAGE(As0, Bs0, 0);
  for (int k0 = 0; k0 < HH; k0 += 64) {
    __syncthreads();                       // drains As0/Bs0 stage (aged by prior compute)
    if (k0 + 32 < HH) GEMM_STAGE(As1, Bs1, k0 + 32);
    GEMM_COMPUTE(As0, Bs0);
    __syncthreads();                       // drains As1/Bs1 stage (aged by compute above)
    if (k0 + 64 < HH) GEMM_STAGE(As0, Bs0, k0 + 64);
    GEMM_COMPUTE(As1, Bs1);
  }
  float bias[4];
#pragma unroll
  for (int j = 0; j < 4; ++j) bias[j] = b1[e * DD + c0 + wc * 64 + j * 16 + l16];
#pragma unroll
  for (int i = 0; i < 4; ++i) {
#pragma unroll
    for (int r = 0; r < 4; ++r) {
      int gr = r0 + wr * 64 + i * 16 + quad * 4 + r;
      if (gr < rend) {
#pragma unroll
        for (int j = 0; j < 4; ++j) {
          int col = c0 + wc * 64 + j * 16 + l16;
          float v = acc[i][j][r] + bias[j];
          v = 0.5f * v * (1.0f + erff(v * 0.70710678118654752f));  // exact erf GELU
          hbuf[(size_t)gr * DD + col] = f2bf(v);
        }
      }
    }
  }
}

// GEMM2: out[perm[row]] = x + h @ Wt2[e] + b2[e]  (A rows contiguous in hbuf)
__global__ __launch_bounds__(256) void k_gemm2(const unsigned short* __restrict__ hbuf,
                                               const unsigned short* __restrict__ Wt2,
                                               const float* __restrict__ b2,
                                               const float* __restrict__ x,
                                               const int* __restrict__ perm,
                                               const int* __restrict__ tileE,
                                               const int* __restrict__ tileR0,
                                               const int* __restrict__ tileEnd,
                                               const int* __restrict__ nTiles,
                                               float* __restrict__ outp) {
  int tile = blockIdx.y;
  if (tile >= *nTiles) return;
  int e = tileE[tile], r0 = tileR0[tile], rend = tileEnd[tile];
  int c0 = blockIdx.x * 128;
  __shared__ __align__(16) unsigned short As0[128 * 32];
  __shared__ __align__(16) unsigned short Bs0[128 * 32];
  __shared__ __align__(16) unsigned short As1[128 * 32];
  __shared__ __align__(16) unsigned short Bs1[128 * 32];
  int tid = threadIdx.x, lane = tid & 63, w = tid >> 6;
  int wr = w >> 1, wc = w & 1;
  int quad = lane >> 4, l16 = lane & 15;
  int srow = lane >> 2, seg = lane & 3;
  int ar0 = w * 32 + srow, ar1 = ar0 + 16;
  int g0 = r0 + ar0; if (g0 >= rend) g0 = rend - 1;
  int g1 = r0 + ar1; if (g1 >= rend) g1 = rend - 1;
  const unsigned short* aG0 = hbuf + (size_t)g0 * DD + seg * 8;
  const unsigned short* aG1 = hbuf + (size_t)g1 * DD + seg * 8;
  const unsigned short* bBase = Wt2 + (size_t)e * ((size_t)HH * DD);
  const unsigned short* bG0 = bBase + (size_t)(c0 + ar0) * DD + seg * 8;
  const unsigned short* bG1 = bBase + (size_t)(c0 + ar1) * DD + seg * 8;
  const int base0 = (w * 32 + 0) * 32, base1 = (w * 32 + 16) * 32;
  f32x4 acc[4][4] = {};
  GEMM_STAGE(As0, Bs0, 0);
  for (int k0 = 0; k0 < DD; k0 += 64) {
    __syncthreads();
    if (k0 + 32 < DD) GEMM_STAGE(As1, Bs1, k0 + 32);
    GEMM_COMPUTE(As0, Bs0);
    __syncthreads();
    if (k0 + 64 < DD) GEMM_STAGE(As0, Bs0, k0 + 64);
    GEMM_COMPUTE(As1, Bs1);
  }
  float bias[4];
#pragma unroll
  for (int j = 0; j < 4; ++j) bias[j] = b2[e * HH + c0 + wc * 64 + j * 16 + l16];
#pragma unroll
  for (int i = 0; i < 4; ++i) {
#pragma unroll
    for (int r = 0; r < 4; ++r) {
      int gr = r0 + wr * 64 + i * 16 + quad * 4 + r;
      if (gr < rend) {
        int tok = perm[gr];
#pragma unroll
        for (int j = 0; j < 4; ++j) {
          int col = c0 + wc * 64 + j * 16 + l16;
          size_t oi = (size_t)tok * HH + col;
          outp[oi] = x[oi] + bias[j] + acc[i][j][r];
        }
      }
    }
  }
}

extern "C" void kernel_launch(void* const* d_in, const int* in_sizes, int n_in,
                              void* d_out, int out_size, void* d_ws, size_t ws_size,
                              hipStream_t stream) {
  const float* x  = (const float*)d_in[0];
  const float* Wr = (const float*)d_in[1];
  const float* br = (const float*)d_in[2];
  const float* W1 = (const float*)d_in[3];
  const float* b1 = (const float*)d_in[4];
  const float* W2 = (const float*)d_in[5];
  const float* b2 = (const float*)d_in[6];
  float* outp = (float*)d_out;

  char* ws = (char*)d_ws;
  int*   counts    = (int*)(ws + 0);
  int*   cursor    = (int*)(ws + 64);
  int*   nTiles    = (int*)(ws + 128);
  float* probs_sum = (float*)(ws + 192);
  float* ent_sum   = (float*)(ws + 256);
  int*   offsets   = (int*)(ws + 320);
  int*   ticket    = (int*)(ws + 448);
  int*   tileE     = (int*)(ws + 512);
  int*   tileR0    = (int*)(ws + 2048);
  int*   tileEnd   = (int*)(ws + 3584);
  int*   eidx      = (int*)(ws + 8192);
  int*   perm      = (int*)(ws + 8192 + 4 * (size_t)TT);
  size_t off = 8192 + 8 * (size_t)TT;
  unsigned short* xb   = (unsigned short*)(ws + off); off += (size_t)TT * HH * 2;        // 32 MB
  unsigned short* Wt1  = (unsigned short*)(ws + off); off += (size_t)EE * DD * HH * 2;   // 32 MB
  unsigned short* Wt2  = (unsigned short*)(ws + off); off += (size_t)EE * HH * DD * 2;   // 32 MB
  unsigned short* hbuf = (unsigned short*)(ws + off); off += (size_t)TT * DD * 2;        // 64 MB

  float* out_scalars = outp + (size_t)TT * HH;

  k_transpose2<<<2 * EE * (HH / 64) * (DD / 64), 256, 0, stream>>>(
      W1, Wt1, W2, Wt2, counts, probs_sum, ent_sum, ticket);
  k_router<<<TT / 16, 256, 0, stream>>>(x, Wr, br, eidx, probs_sum, ent_sum, counts, xb,
                                        ticket, offsets, cursor, tileE, tileR0, tileEnd,
                                        nTiles, out_scalars);
  k_perm<<<TT / 256, 256, 0, stream>>>(eidx, cursor, perm);
  dim3 g1(DD / 128, MAXTILES);
  k_gemm1<<<g1, 256, 0, stream>>>(xb, Wt1, b1, perm, tileE, tileR0, tileEnd, nTiles, hbuf);
  dim3 g2(HH / 128, MAXTILES);
  k_gemm2<<<g2, 256, 0, stream>>>(hbuf, Wt2, b2, x, perm, tileE, tileR0, tileEnd, nTiles, outp);
}